// Round 17
// baseline (126.223 us; speedup 1.0000x reference)
//
#include <hip/hip_runtime.h>

typedef __attribute__((ext_vector_type(8))) short short8;
typedef __attribute__((ext_vector_type(4))) float f32x4;
typedef __attribute__((ext_vector_type(16))) float f32x16;

#define LOG2E 1.4426950408889634f
#define QSCALE 0.18033688011112042f   // 0.125 * LOG2E, folded into Q

#define ASM_VMCNT2() asm volatile("s_waitcnt vmcnt(2)" ::: "memory")
#define ASM_VMCNT1() asm volatile("s_waitcnt vmcnt(1)" ::: "memory")
#define ASM_VMCNT0() asm volatile("s_waitcnt vmcnt(0)" ::: "memory")
#define ASM_LGKM0()  asm volatile("s_waitcnt lgkmcnt(0)" ::: "memory")

static __device__ __forceinline__ unsigned short f2bf(float f){
  unsigned u = __builtin_bit_cast(unsigned, f);
  u += 0x7FFFu + ((u>>16)&1u);
  return (unsigned short)(u>>16);
}
static __device__ __forceinline__ float bf2f(unsigned short u){
  return __builtin_bit_cast(float, ((unsigned)u)<<16);
}

static __device__ __forceinline__ void async16(const void* g, const void* l){
  __builtin_amdgcn_global_load_lds(
      (const __attribute__((address_space(1))) unsigned*)(unsigned long long)g,
      (__attribute__((address_space(3))) unsigned*)(unsigned)(unsigned long long)l,
      16, 0, 0);
}

// ---------------- prep: fp32->bf16 casts + mask*LOG2E, one launch ----------------
__global__ __launch_bounds__(256) void prep_kernel(
    const float* __restrict__ hidden, unsigned short* __restrict__ hb,
    const float* __restrict__ encoder, unsigned short* __restrict__ eb,
    const float* __restrict__ Wq, unsigned short* __restrict__ wqb,
    const float* __restrict__ Wk, unsigned short* __restrict__ wkb,
    const float* __restrict__ Wv, unsigned short* __restrict__ wvb,
    const float* __restrict__ Wd, unsigned short* __restrict__ wdb,
    const float* __restrict__ mask, float* __restrict__ maskE)
{
  int blk = blockIdx.x;
  if (blk < 6144){
    const float* src; unsigned short* dst; int i;
    if (blk < 4096){
      int t = blk*256 + threadIdx.x;
      src = (t >> 19) ? encoder : hidden;
      dst = (t >> 19) ? eb : hb;
      i = (t & 524287)*8;
    } else {
      int t = (blk-4096)*256 + threadIdx.x;
      int z = t >> 17;
      src = (z==0)?Wq:(z==1)?Wk:(z==2)?Wv:Wd;
      dst = (z==0)?wqb:(z==1)?wkb:(z==2)?wvb:wdb;
      i = (t & 131071)*8;
    }
    const float4* s4 = (const float4*)(src + i);
    float4 a = s4[0], b = s4[1];
    union { unsigned short u[8]; short8 v; } o;
    o.u[0]=f2bf(a.x); o.u[1]=f2bf(a.y); o.u[2]=f2bf(a.z); o.u[3]=f2bf(a.w);
    o.u[4]=f2bf(b.x); o.u[5]=f2bf(b.y); o.u[6]=f2bf(b.z); o.u[7]=f2bf(b.w);
    *(short8*)(dst + i) = o.v;
  } else {
    int i = (blk-6144)*256 + threadIdx.x;
    float4 v = ((const float4*)mask)[i];
    v.x*=LOG2E; v.y*=LOG2E; v.z*=LOG2E; v.w*=LOG2E;
    ((float4*)maskE)[i] = v;
  }
}

// ---------------- QKV GEMM: 128x128 tile, 512 threads, triple-buffered single-barrier ----
__global__ __launch_bounds__(512) void gemm_qkv(
    const unsigned short* __restrict__ hb, const unsigned short* __restrict__ eb,
    const unsigned short* __restrict__ wqb, const unsigned short* __restrict__ wkb,
    const unsigned short* __restrict__ wvb,
    const float* __restrict__ bq, const float* __restrict__ bk, const float* __restrict__ bv,
    const float* __restrict__ sp, const float* __restrict__ csp,
    unsigned short* __restrict__ Qb, unsigned short* __restrict__ Kb, unsigned short* __restrict__ Vt)
{
  const int flat = blockIdx.x;
  const int work = (flat&7)*96 + (flat>>3);
  const int bn  = work & 7;
  const int zbm = work >> 3;       // 0..95, z-major
  const int z  = zbm >> 5;
  const int bm = zbm & 31;

  const unsigned short* A = (z==0) ? hb : eb;
  const unsigned short* W = (z==0) ? wqb : (z==1 ? wkb : wvb);
  const float* bias = (z==0) ? bq : (z==1 ? bk : bv);
  const float* rope = (z==0) ? sp : (z==1 ? csp : nullptr);

  __shared__ unsigned short As[3][128*32];
  __shared__ unsigned short Bs[3][128*32];

  const int tid = threadIdx.x;
  const int w = tid>>6, l = tid&63;
  const int wr = w>>1, wc = w&1;
  const int srow = tid>>2, scol = (tid&3)*8;

  const f32x4 zero = {0.f,0.f,0.f,0.f};
  f32x4 acc[2][4];
  #pragma unroll
  for (int mi=0;mi<2;mi++)
    #pragma unroll
    for (int ni=0;ni<4;ni++) acc[mi][ni] = zero;

  auto stage = [&](int buf, int kt){
    async16(A + (size_t)(bm*128 + srow)*1024 + kt*32 + scol, As[buf] + tid*8);
    async16(W + (size_t)(bn*128 + srow)*1024 + kt*32 + scol, Bs[buf] + tid*8);
  };

  stage(0, 0);

  int cur = 0;
  for (int kt=0; kt<32; ++kt){
    int nxt = (cur==2) ? 0 : cur+1;
    if (kt < 31){ stage(nxt, kt+1); ASM_VMCNT2(); }
    else        { ASM_VMCNT0(); }
    __builtin_amdgcn_s_barrier();
    __builtin_amdgcn_sched_barrier(0);

    short8 af[2], bf[4];
    #pragma unroll
    for (int mi=0;mi<2;mi++)
      af[mi] = *(const short8*)(As[cur] + (wr*32 + mi*16 + (l&15))*32 + (l>>4)*8);
    #pragma unroll
    for (int ni=0;ni<4;ni++)
      bf[ni] = *(const short8*)(Bs[cur] + (wc*64 + ni*16 + (l&15))*32 + (l>>4)*8);
    #pragma unroll
    for (int mi=0;mi<2;mi++)
      #pragma unroll
      for (int ni=0;ni<4;ni++)
        acc[mi][ni] = __builtin_amdgcn_mfma_f32_16x16x32_bf16(af[mi], bf[ni], acc[mi][ni], 0,0,0);

    cur = nxt;
  }

  if (z == 2){
    #pragma unroll
    for (int mi=0;mi<2;mi++){
      #pragma unroll
      for (int ni=0;ni<4;ni++){
        int mr0 = bm*128 + wr*32 + mi*16 + (l>>4)*4;
        int nc  = bn*128 + wc*64 + ni*16 + (l&15);
        int b0 = mr0>>11, s0 = mr0&2047;
        int h = nc>>6, d = nc&63;
        float bia = bias[nc];
        union { unsigned short u[4]; unsigned long long ull; } pk;
        #pragma unroll
        for (int r=0;r<4;r++) pk.u[r] = f2bf(acc[mi][ni][r] + bia);
        *(unsigned long long*)(Vt + ((size_t)(b0*16 + h)*64 + d)*2048 + s0) = pk.ull;
      }
    }
  } else {
    #pragma unroll
    for (int mi=0;mi<2;mi++){
      #pragma unroll
      for (int ni=0;ni<4;ni++){
        #pragma unroll
        for (int r=0;r<4;r++){
          int mr = bm*128 + wr*32 + mi*16 + (l>>4)*4 + r;
          int nc = bn*128 + wc*64 + ni*16 + (l&15);
          float v = acc[mi][ni][r] + bias[nc];
          int b = mr>>11, s = mr&2047;
          int h = nc>>6,  d = nc&63;
          float p = __shfl_xor(v, 1);
          float sv = rope[s*64 + (d>>1)];
          float cv = rope[s*64 + 32 + (d>>1)];
          float ov = (d&1) ? (v*cv + p*sv) : (v*cv - p*sv);
          if (z == 0) ov *= QSCALE;
          unsigned short* out = (z==0) ? Qb : Kb;
          out[((size_t)(b*16 + h)*2048 + s)*64 + d] = f2bf(ov);
        }
      }
    }
  }
}

// ---------------- flash attention: 8 waves, KV-split; guard moved after PV ----------------
__global__ __launch_bounds__(512) void flash_attn(
    const unsigned short* __restrict__ Qb, const unsigned short* __restrict__ Kb,
    const unsigned short* __restrict__ Vt, const float* __restrict__ maskE,
    unsigned short* __restrict__ ctx)
{
  __shared__ unsigned short Kls[2][2][4096];   // [half][dbuf][64 kv][64 d] swizzled
  __shared__ unsigned short Vls[2][2][4096];   // [half][dbuf] V^T tiles swizzled
  __shared__ float maskLS[2048];               // mask * LOG2E for this b

  const int tid = threadIdx.x;
  const int w = tid>>6, l = tid&63;
  const int qc = l&31, hi = l>>5;
  const int wq = w&3, half = w>>2;

  const int flat = blockIdx.x;              // 0..511
  const int o = (flat&7)*64 + (flat>>3);
  const int qt = o&15, bh = o>>4;
  const int b = bh>>4, h = bh&15;

  { // stage mask row (pre-scaled) into LDS: 512 threads x float4 = 2048 floats
    ((float4*)maskLS)[tid] = ((const float4*)(maskE + b*2048))[tid];
  }

  // Q fragments (B-operand of swapped QK^T); Q already scaled by 0.125*LOG2E
  const int qrow = qt*128 + wq*32 + qc;
  const unsigned short* qptr = Qb + ((size_t)bh*2048 + qrow)*64;
  short8 qf[4];
  #pragma unroll
  for (int ks=0;ks<4;ks++) qf[ks] = *(const short8*)(qptr + ks*16 + hi*8);

  float m_r = 0.f, l_r = 0.f;    // max-free: m_r only changes on rare renormalize
  f32x16 oacc[2];
  #pragma unroll
  for (int t3=0;t3<2;t3++)
    #pragma unroll
    for (int i=0;i<16;i++) oacc[t3][i] = 0.f;

  const int srow = l>>3;
  const int scol = ((l&7) ^ srow)*8;
  const unsigned short* kSrc0; const unsigned short* kSrc1;
  const unsigned short* vSrc0; const unsigned short* vSrc1;
  {
    int c0 = wq*2, c1 = wq*2+1;
    kSrc0 = Kb + ((size_t)bh*2048 + half*1024 + c0*8 + srow)*64 + scol;
    kSrc1 = Kb + ((size_t)bh*2048 + half*1024 + c1*8 + srow)*64 + scol;
    vSrc0 = Vt + ((size_t)bh*64 + c0*8 + srow)*2048 + half*1024 + scol;
    vSrc1 = Vt + ((size_t)bh*64 + c1*8 + srow)*2048 + half*1024 + scol;
  }
  const int ld0 = (wq*2)*512 + l*8, ld1 = (wq*2+1)*512 + l*8;

  auto stage = [&](int buf){
    async16(kSrc0, &Kls[half][buf][ld0]);
    async16(kSrc1, &Kls[half][buf][ld1]);
    async16(vSrc0, &Vls[half][buf][ld0]);
    async16(vSrc1, &Vls[half][buf][ld1]);
    kSrc0 += 4096; kSrc1 += 4096;
    vSrc0 += 64;   vSrc1 += 64;
  };

  stage(0);
  __syncthreads();
  int cur = 0;

  const int rg0 = (qc&7);   // read-swizzle key

  for (int ktl=0; ktl<16; ++ktl){
    if (ktl < 15) stage(cur^1);

    // C-init = mask (pre-scaled by LOG2E): S comes out of MFMA already masked
    f32x16 sacc[2];
    #pragma unroll
    for (int t2=0;t2<2;t2++){
      #pragma unroll
      for (int rg=0;rg<4;rg++){
        const float4 mv = *(const float4*)&maskLS[half*1024 + ktl*64 + t2*32 + rg*8 + hi*4];
        sacc[t2][rg*4+0] = mv.x;
        sacc[t2][rg*4+1] = mv.y;
        sacc[t2][rg*4+2] = mv.z;
        sacc[t2][rg*4+3] = mv.w;
      }
    }

    __builtin_amdgcn_s_setprio(1);
    #pragma unroll
    for (int ks=0; ks<4; ++ks){
      const short8 kf0 = *(const short8*)(&Kls[half][cur][ qc*64      + (((ks*2+hi)^rg0)*8) ]);
      const short8 kf1 = *(const short8*)(&Kls[half][cur][ (32+qc)*64 + (((ks*2+hi)^rg0)*8) ]);
      sacc[0] = __builtin_amdgcn_mfma_f32_32x32x16_bf16(kf0, qf[ks], sacc[0], 0,0,0);
      sacc[1] = __builtin_amdgcn_mfma_f32_32x32x16_bf16(kf1, qf[ks], sacc[1], 0,0,0);
    }
    __builtin_amdgcn_s_setprio(0);

    // max-free softmax: e = 2^(s - m_r); rs/cm computed but guard DEFERRED past PV
    float rs = 0.f, cm = 1.0f;
    #pragma unroll
    for (int t2=0;t2<2;t2++)
      #pragma unroll
      for (int i=0;i<16;i++){
        float e = __builtin_amdgcn_exp2f(sacc[t2][i] - m_r);
        sacc[t2][i] = e;
        rs += e;
        cm = fmaxf(cm, e);
      }

    // P -> PV B-fragments fully in-register (independent of rs/cm)
    short8 pB[4];
    #pragma unroll
    for (int t2=0;t2<2;t2++){
      #pragma unroll
      for (int hf=0; hf<2; ++hf){
        unsigned x0,x1,x2,x3;
        asm("v_cvt_pk_bf16_f32 %0, %1, %2" : "=v"(x0) : "v"(sacc[t2][hf*8+0]), "v"(sacc[t2][hf*8+1]));
        asm("v_cvt_pk_bf16_f32 %0, %1, %2" : "=v"(x1) : "v"(sacc[t2][hf*8+2]), "v"(sacc[t2][hf*8+3]));
        asm("v_cvt_pk_bf16_f32 %0, %1, %2" : "=v"(x2) : "v"(sacc[t2][hf*8+4]), "v"(sacc[t2][hf*8+5]));
        asm("v_cvt_pk_bf16_f32 %0, %1, %2" : "=v"(x3) : "v"(sacc[t2][hf*8+6]), "v"(sacc[t2][hf*8+7]));
        asm("v_permlane32_swap_b32 %0, %1" : "+v"(x2), "+v"(x0));
        asm("v_permlane32_swap_b32 %0, %1" : "+v"(x3), "+v"(x1));
        union { unsigned u[4]; short8 v; } pb;
        pb.u[0]=x0; pb.u[1]=x1; pb.u[2]=x2; pb.u[3]=x3;
        pB[t2*2+hf] = pb.v;
      }
    }

    // O^T += V^T P^T  (rs cross-lane sum overlaps these MFMAs)
    __builtin_amdgcn_s_setprio(1);
    #pragma unroll
    for (int t3=0;t3<2;t3++){
      #pragma unroll
      for (int si=0; si<4; ++si){
        const short8 vf = *(const short8*)(&Vls[half][cur][ (t3*32+qc)*64 + (((si*2+hi)^rg0)*8) ]);
        oacc[t3] = __builtin_amdgcn_mfma_f32_32x32x16_bf16(vf, pB[si], oacc[t3], 0,0,0);
      }
    }
    __builtin_amdgcn_s_setprio(0);

    { float a = rs, c2 = rs;
      asm("v_permlane32_swap_b32 %0, %1" : "+v"(a), "+v"(c2));
      rs = a + c2; }

    // deferred guard: renormalizing AFTER PV divides everything accumulated
    // so far (incl. tile t) by cm — mathematically identical
    if (__builtin_expect(!__all(rs <= 16777216.0f), 0)){
      { float a = cm, c2 = cm;
        asm("v_permlane32_swap_b32 %0, %1" : "+v"(a), "+v"(c2));
        cm = fmaxf(a, c2); }
      float rin = 1.0f/cm;
      #pragma unroll
      for (int t3=0;t3<2;t3++)
        #pragma unroll
        for (int i=0;i<16;i++) oacc[t3][i] *= rin;
      l_r *= rin;
      rs  *= rin;
      m_r += log2f(cm);
    }
    l_r += rs;

    __syncthreads();
    cur ^= 1;
  }

  // ---- combine halves through LDS (reuse K/V buffers) ----
  float* Ox  = (float*)&Kls[0][0][0];   // 32 KB: [wq][32 q][64 d] swizzled
  float* MLf = (float*)&Vls[0][0][0];   // [wq][ {m:32, l:32} ]

  if (half == 1){
    #pragma unroll
    for (int t3=0;t3<2;t3++){
      #pragma unroll
      for (int rg=0;rg<4;rg++){
        int dbase = t3*32 + rg*8 + hi*4;
        f32x4 o4 = { oacc[t3][rg*4+0], oacc[t3][rg*4+1], oacc[t3][rg*4+2], oacc[t3][rg*4+3] };
        *(f32x4*)&Ox[wq*2048 + qc*64 + (dbase ^ (rg0*8))] = o4;
      }
    }
    if (hi == 0){
      MLf[wq*64 + qc]      = m_r;
      MLf[wq*64 + 32 + qc] = l_r;
    }
  }
  __syncthreads();

  if (half == 0){
    float m1 = MLf[wq*64 + qc];
    float l1 = MLf[wq*64 + 32 + qc];
    float mstar = fmaxf(m_r, m1);
    float s0 = __builtin_amdgcn_exp2f(m_r - mstar);
    float s1 = __builtin_amdgcn_exp2f(m1 - mstar);
    float inv = 1.0f / (l_r*s0 + l1*s1);
    float a0 = s0*inv, a1 = s1*inv;

    int qglob = qt*128 + wq*32 + qc;
    unsigned short* cp = ctx + ((size_t)b*2048 + qglob)*1024 + h*64;
    #pragma unroll
    for (int t3=0;t3<2;t3++){
      #pragma unroll
      for (int rg=0;rg<4;rg++){
        int dbase = t3*32 + rg*8 + hi*4;
        f32x4 o1 = *(const f32x4*)&Ox[wq*2048 + qc*64 + (dbase ^ (rg0*8))];
        union { unsigned short u[4]; unsigned long long ull; } pk4;
        #pragma unroll
        for (int i=0;i<4;i++) pk4.u[i] = f2bf(oacc[t3][rg*4+i]*a0 + o1[i]*a1);
        *(unsigned long long*)(cp + dbase) = pk4.ull;
      }
    }
  }
}

// ---------------- proj GEMM: 64x128 tile, 512 threads; residual from bf16 hb; X bf16 ----
__global__ __launch_bounds__(512) void gemm_proj(
    const unsigned short* __restrict__ ctxb, const unsigned short* __restrict__ wdb,
    const float* __restrict__ bd, const unsigned short* __restrict__ hb,
    unsigned short* __restrict__ X)
{
  const int flat = blockIdx.x;              // 0..511
  const int work = (flat&7)*64 + (flat>>3);
  const int bn = work & 7;
  const int bm = work >> 3;

  __shared__ unsigned short As[3][64*32];
  __shared__ unsigned short Bs[3][128*32];
  const int tid = threadIdx.x;
  const int w = tid>>6, l = tid&63;
  const int wr = w>>2, wc = w&3;

  const f32x4 zero = {0.f,0.f,0.f,0.f};
  f32x4 acc[2][2];
  #pragma unroll
  for (int mi=0;mi<2;mi++)
    #pragma unroll
    for (int ni=0;ni<2;ni++) acc[mi][ni] = zero;

  auto stage = [&](int buf, int kt){
    if (tid < 256)
      async16(ctxb + (size_t)(bm*64 + (tid>>2))*1024 + kt*32 + (tid&3)*8, As[buf] + tid*8);
    async16(wdb + (size_t)(bn*128 + (tid>>2))*1024 + kt*32 + (tid&3)*8, Bs[buf] + tid*8);
  };

  stage(0, 0);

  int cur = 0;
  for (int kt=0; kt<32; ++kt){
    int nxt = (cur==2) ? 0 : cur+1;
    if (kt < 31){
      stage(nxt, kt+1);
      if (w < 4) ASM_VMCNT2(); else ASM_VMCNT1();
    } else {
      ASM_VMCNT0();
    }
    __builtin_amdgcn_s_barrier();
    __builtin_amdgcn_sched_barrier(0);

    short8 af[2], bf[2];
    #pragma unroll
    for (int mi=0;mi<2;mi++)
      af[mi] = *(const short8*)(As[cur] + (wr*32 + mi*16 + (l&15))*32 + (l>>4)*8);
    #pragma unroll
    for (int ni=0;ni<2;ni++)
      bf[ni] = *(const short8*)(Bs[cur] + (wc*32 + ni*16 + (l&15))*32 + (l>>4)*8);
    #pragma unroll
    for (int mi=0;mi<2;mi++)
      #pragma unroll
      for (int ni=0;ni<2;ni++)
        acc[mi][ni] = __builtin_amdgcn_mfma_f32_16x16x32_bf16(af[mi], bf[ni], acc[mi][ni], 0,0,0);

    cur = nxt;
  }

  #pragma unroll
  for (int mi=0;mi<2;mi++){
    #pragma unroll
    for (int ni=0;ni<2;ni++){
      #pragma unroll
      for (int r=0;r<4;r++){
        int mr = bm*64 + wr*32 + mi*16 + (l>>4)*4 + r;
        int nc = bn*128 + wc*32 + ni*16 + (l&15);
        float v = acc[mi][ni][r] + bd[nc] + bf2f(hb[(size_t)mr*1024 + nc]);
        X[(size_t)mr*1024 + nc] = f2bf(v);
      }
    }
  }
}

// ---------------- LayerNorm over 1024 (bf16 X in, fp32 out), one block per row ----------------
__global__ __launch_bounds__(256) void ln_kernel(
    const unsigned short* __restrict__ X, const float* __restrict__ gamma,
    const float* __restrict__ beta, float* __restrict__ out)
{
  const int row = blockIdx.x;
  const int tid = threadIdx.x;
  uint2 raw = ((const uint2*)(X + (size_t)row*1024))[tid];
  float v0 = __builtin_bit_cast(float, (raw.x & 0xFFFFu) << 16);
  float v1 = __builtin_bit_cast(float, raw.x & 0xFFFF0000u);
  float v2 = __builtin_bit_cast(float, (raw.y & 0xFFFFu) << 16);
  float v3 = __builtin_bit_cast(float, raw.y & 0xFFFF0000u);
  float s  = v0+v1+v2+v3;
  float ss = v0*v0 + v1*v1 + v2*v2 + v3*v3;
  #pragma unroll
  for (int off=1; off<64; off<<=1){
    s  += __shfl_xor(s, off);
    ss += __shfl_xor(ss, off);
  }
  __shared__ float red[8];
  const int w = tid>>6, l = tid&63;
  if (l == 0){ red[w] = s; red[4+w] = ss; }
  __syncthreads();
  s  = red[0]+red[1]+red[2]+red[3];
  ss = red[4]+red[5]+red[6]+red[7];
  float mu  = s*(1.f/1024.f);
  float var = ss*(1.f/1024.f) - mu*mu;
  float inv = rsqrtf(var + 1e-12f);
  const float4 g  = ((const float4*)gamma)[tid];
  const float4 bt = ((const float4*)beta)[tid];
  float4 oo;
  oo.x = (v0-mu)*inv*g.x + bt.x;
  oo.y = (v1-mu)*inv*g.y + bt.y;
  oo.z = (v2-mu)*inv*g.z + bt.z;
  oo.w = (v3-mu)*inv*g.w + bt.w;
  ((float4*)(out + (size_t)row*1024))[tid] = oo;
}

extern "C" void kernel_launch(void* const* d_in, const int* in_sizes, int n_in,
                              void* d_out, int out_size, void* d_ws, size_t ws_size,
                              hipStream_t stream) {
  const float* hidden  = (const float*)d_in[0];
  const float* encoder = (const float*)d_in[1];
  const float* mask    = (const float*)d_in[2];
  const float* sp      = (const float*)d_in[3];
  const float* csp     = (const float*)d_in[4];
  const float* Wq = (const float*)d_in[5];  const float* bq = (const float*)d_in[6];
  const float* Wk = (const float*)d_in[7];  const float* bk = (const float*)d_in[8];
  const float* Wv = (const float*)d_in[9];  const float* bv = (const float*)d_in[10];
  const float* Wd = (const float*)d_in[11]; const float* bd = (const float*)d_in[12];
  const float* gamma = (const float*)d_in[13];
  const float* beta  = (const float*)d_in[14];

  char* ws = (char*)d_ws;
  const size_t MB_ = 1ull<<20;
  unsigned short* hb  = (unsigned short*)(ws + 0);        // 8 MB (stays live for residual)
  unsigned short* eb  = (unsigned short*)(ws + 8*MB_);    // 8 MB; reused as ctx after qkv
  unsigned short* wqb = (unsigned short*)(ws + 16*MB_);   // 2 MB
  unsigned short* wkb = (unsigned short*)(ws + 18*MB_);   // 2 MB
  unsigned short* wvb = (unsigned short*)(ws + 20*MB_);   // 2 MB
  unsigned short* wdb = (unsigned short*)(ws + 22*MB_);   // 2 MB
  unsigned short* Qb  = (unsigned short*)(ws + 24*MB_);   // 8 MB; reused as X (bf16) after flash
  unsigned short* Kb  = (unsigned short*)(ws + 32*MB_);   // 8 MB
  unsigned short* Vt  = (unsigned short*)(ws + 40*MB_);   // 8 MB
  unsigned short* ctxb = eb;
  unsigned short* X = Qb;
  float* maskE = (float*)(ws + 48*MB_);                   // 16 KB

  prep_kernel<<<6148,256,0,stream>>>(hidden, hb, encoder, eb,
                                     Wq, wqb, Wk, wkb, Wv, wvb, Wd, wdb,
                                     mask, maskE);

  gemm_qkv<<<768,512,0,stream>>>(hb, eb, wqb, wkb, wvb,
                                 bq, bk, bv, sp, csp, Qb, Kb, Vt);
  flash_attn<<<512,512,0,stream>>>(Qb, Kb, Vt, maskE, ctxb);
  gemm_proj<<<512,512,0,stream>>>(ctxb, wdb, bd, hb, X);
  ln_kernel<<<4096,256,0,stream>>>(X, gamma, beta, (float*)d_out);
}

// Round 18
// 120.210 us; speedup vs baseline: 1.0500x; 1.0500x over previous
//
#include <hip/hip_runtime.h>

typedef __attribute__((ext_vector_type(8))) short short8;
typedef __attribute__((ext_vector_type(4))) float f32x4;
typedef __attribute__((ext_vector_type(16))) float f32x16;

#define LOG2E 1.4426950408889634f
#define QSCALE 0.18033688011112042f   // 0.125 * LOG2E, folded into Q

#define ASM_VMCNT2() asm volatile("s_waitcnt vmcnt(2)" ::: "memory")
#define ASM_VMCNT1() asm volatile("s_waitcnt vmcnt(1)" ::: "memory")
#define ASM_VMCNT0() asm volatile("s_waitcnt vmcnt(0)" ::: "memory")
#define ASM_LGKM0()  asm volatile("s_waitcnt lgkmcnt(0)" ::: "memory")

static __device__ __forceinline__ unsigned short f2bf(float f){
  unsigned u = __builtin_bit_cast(unsigned, f);
  u += 0x7FFFu + ((u>>16)&1u);
  return (unsigned short)(u>>16);
}
static __device__ __forceinline__ float bf2f(unsigned short u){
  return __builtin_bit_cast(float, ((unsigned)u)<<16);
}

static __device__ __forceinline__ void async16(const void* g, const void* l){
  __builtin_amdgcn_global_load_lds(
      (const __attribute__((address_space(1))) unsigned*)(unsigned long long)g,
      (__attribute__((address_space(3))) unsigned*)(unsigned)(unsigned long long)l,
      16, 0, 0);
}

// ---------------- prep: fp32->bf16 casts + mask*LOG2E, one launch ----------------
__global__ __launch_bounds__(256) void prep_kernel(
    const float* __restrict__ hidden, unsigned short* __restrict__ hb,
    const float* __restrict__ encoder, unsigned short* __restrict__ eb,
    const float* __restrict__ Wq, unsigned short* __restrict__ wqb,
    const float* __restrict__ Wk, unsigned short* __restrict__ wkb,
    const float* __restrict__ Wv, unsigned short* __restrict__ wvb,
    const float* __restrict__ Wd, unsigned short* __restrict__ wdb,
    const float* __restrict__ mask, float* __restrict__ maskE)
{
  int blk = blockIdx.x;
  if (blk < 6144){
    const float* src; unsigned short* dst; int i;
    if (blk < 4096){
      int t = blk*256 + threadIdx.x;
      src = (t >> 19) ? encoder : hidden;
      dst = (t >> 19) ? eb : hb;
      i = (t & 524287)*8;
    } else {
      int t = (blk-4096)*256 + threadIdx.x;
      int z = t >> 17;
      src = (z==0)?Wq:(z==1)?Wk:(z==2)?Wv:Wd;
      dst = (z==0)?wqb:(z==1)?wkb:(z==2)?wvb:wdb;
      i = (t & 131071)*8;
    }
    const float4* s4 = (const float4*)(src + i);
    float4 a = s4[0], b = s4[1];
    union { unsigned short u[8]; short8 v; } o;
    o.u[0]=f2bf(a.x); o.u[1]=f2bf(a.y); o.u[2]=f2bf(a.z); o.u[3]=f2bf(a.w);
    o.u[4]=f2bf(b.x); o.u[5]=f2bf(b.y); o.u[6]=f2bf(b.z); o.u[7]=f2bf(b.w);
    *(short8*)(dst + i) = o.v;
  } else {
    int i = (blk-6144)*256 + threadIdx.x;
    float4 v = ((const float4*)mask)[i];
    v.x*=LOG2E; v.y*=LOG2E; v.z*=LOG2E; v.w*=LOG2E;
    ((float4*)maskE)[i] = v;
  }
}

// ---------------- QKV GEMM: 128x128 tile, 512 threads, triple-buffered single-barrier ----
__global__ __launch_bounds__(512) void gemm_qkv(
    const unsigned short* __restrict__ hb, const unsigned short* __restrict__ eb,
    const unsigned short* __restrict__ wqb, const unsigned short* __restrict__ wkb,
    const unsigned short* __restrict__ wvb,
    const float* __restrict__ bq, const float* __restrict__ bk, const float* __restrict__ bv,
    const float* __restrict__ sp, const float* __restrict__ csp,
    unsigned short* __restrict__ Qb, unsigned short* __restrict__ Kb, unsigned short* __restrict__ Vt)
{
  const int flat = blockIdx.x;
  const int work = (flat&7)*96 + (flat>>3);
  const int bn  = work & 7;
  const int zbm = work >> 3;       // 0..95, z-major
  const int z  = zbm >> 5;
  const int bm = zbm & 31;

  const unsigned short* A = (z==0) ? hb : eb;
  const unsigned short* W = (z==0) ? wqb : (z==1 ? wkb : wvb);
  const float* bias = (z==0) ? bq : (z==1 ? bk : bv);
  const float* rope = (z==0) ? sp : (z==1 ? csp : nullptr);

  __shared__ unsigned short As[3][128*32];
  __shared__ unsigned short Bs[3][128*32];

  const int tid = threadIdx.x;
  const int w = tid>>6, l = tid&63;
  const int wr = w>>1, wc = w&1;
  const int srow = tid>>2, scol = (tid&3)*8;

  const f32x4 zero = {0.f,0.f,0.f,0.f};
  f32x4 acc[2][4];
  #pragma unroll
  for (int mi=0;mi<2;mi++)
    #pragma unroll
    for (int ni=0;ni<4;ni++) acc[mi][ni] = zero;

  auto stage = [&](int buf, int kt){
    async16(A + (size_t)(bm*128 + srow)*1024 + kt*32 + scol, As[buf] + tid*8);
    async16(W + (size_t)(bn*128 + srow)*1024 + kt*32 + scol, Bs[buf] + tid*8);
  };

  stage(0, 0);

  int cur = 0;
  for (int kt=0; kt<32; ++kt){
    int nxt = (cur==2) ? 0 : cur+1;
    if (kt < 31){ stage(nxt, kt+1); ASM_VMCNT2(); }
    else        { ASM_VMCNT0(); }
    __builtin_amdgcn_s_barrier();
    __builtin_amdgcn_sched_barrier(0);

    short8 af[2], bf[4];
    #pragma unroll
    for (int mi=0;mi<2;mi++)
      af[mi] = *(const short8*)(As[cur] + (wr*32 + mi*16 + (l&15))*32 + (l>>4)*8);
    #pragma unroll
    for (int ni=0;ni<4;ni++)
      bf[ni] = *(const short8*)(Bs[cur] + (wc*64 + ni*16 + (l&15))*32 + (l>>4)*8);
    #pragma unroll
    for (int mi=0;mi<2;mi++)
      #pragma unroll
      for (int ni=0;ni<4;ni++)
        acc[mi][ni] = __builtin_amdgcn_mfma_f32_16x16x32_bf16(af[mi], bf[ni], acc[mi][ni], 0,0,0);

    cur = nxt;
  }

  if (z == 2){
    #pragma unroll
    for (int mi=0;mi<2;mi++){
      #pragma unroll
      for (int ni=0;ni<4;ni++){
        int mr0 = bm*128 + wr*32 + mi*16 + (l>>4)*4;
        int nc  = bn*128 + wc*64 + ni*16 + (l&15);
        int b0 = mr0>>11, s0 = mr0&2047;
        int h = nc>>6, d = nc&63;
        float bia = bias[nc];
        union { unsigned short u[4]; unsigned long long ull; } pk;
        #pragma unroll
        for (int r=0;r<4;r++) pk.u[r] = f2bf(acc[mi][ni][r] + bia);
        *(unsigned long long*)(Vt + ((size_t)(b0*16 + h)*64 + d)*2048 + s0) = pk.ull;
      }
    }
  } else {
    #pragma unroll
    for (int mi=0;mi<2;mi++){
      #pragma unroll
      for (int ni=0;ni<4;ni++){
        #pragma unroll
        for (int r=0;r<4;r++){
          int mr = bm*128 + wr*32 + mi*16 + (l>>4)*4 + r;
          int nc = bn*128 + wc*64 + ni*16 + (l&15);
          float v = acc[mi][ni][r] + bias[nc];
          int b = mr>>11, s = mr&2047;
          int h = nc>>6,  d = nc&63;
          float p = __shfl_xor(v, 1);
          float sv = rope[s*64 + (d>>1)];
          float cv = rope[s*64 + 32 + (d>>1)];
          float ov = (d&1) ? (v*cv + p*sv) : (v*cv - p*sv);
          if (z == 0) ov *= QSCALE;
          unsigned short* out = (z==0) ? Qb : Kb;
          out[((size_t)(b*16 + h)*2048 + s)*64 + d] = f2bf(ov);
        }
      }
    }
  }
}

// ---------------- flash attention: 8 waves, KV-split, max-free online softmax (R12/R14/R16) ----
__global__ __launch_bounds__(512) void flash_attn(
    const unsigned short* __restrict__ Qb, const unsigned short* __restrict__ Kb,
    const unsigned short* __restrict__ Vt, const float* __restrict__ maskE,
    unsigned short* __restrict__ ctx)
{
  __shared__ unsigned short Kls[2][2][4096];   // [half][dbuf][64 kv][64 d] swizzled
  __shared__ unsigned short Vls[2][2][4096];   // [half][dbuf] V^T tiles swizzled
  __shared__ float maskLS[2048];               // mask * LOG2E for this b

  const int tid = threadIdx.x;
  const int w = tid>>6, l = tid&63;
  const int qc = l&31, hi = l>>5;
  const int wq = w&3, half = w>>2;

  const int flat = blockIdx.x;              // 0..511
  const int o = (flat&7)*64 + (flat>>3);
  const int qt = o&15, bh = o>>4;
  const int b = bh>>4, h = bh&15;

  { // stage mask row (pre-scaled) into LDS: 512 threads x float4 = 2048 floats
    ((float4*)maskLS)[tid] = ((const float4*)(maskE + b*2048))[tid];
  }

  // Q fragments (B-operand of swapped QK^T); Q already scaled by 0.125*LOG2E
  const int qrow = qt*128 + wq*32 + qc;
  const unsigned short* qptr = Qb + ((size_t)bh*2048 + qrow)*64;
  short8 qf[4];
  #pragma unroll
  for (int ks=0;ks<4;ks++) qf[ks] = *(const short8*)(qptr + ks*16 + hi*8);

  float m_r = 0.f, l_r = 0.f;    // max-free: m_r only changes on rare renormalize
  f32x16 oacc[2];
  #pragma unroll
  for (int t3=0;t3<2;t3++)
    #pragma unroll
    for (int i=0;i<16;i++) oacc[t3][i] = 0.f;

  const int srow = l>>3;
  const int scol = ((l&7) ^ srow)*8;
  const unsigned short* kSrc0; const unsigned short* kSrc1;
  const unsigned short* vSrc0; const unsigned short* vSrc1;
  {
    int c0 = wq*2, c1 = wq*2+1;
    kSrc0 = Kb + ((size_t)bh*2048 + half*1024 + c0*8 + srow)*64 + scol;
    kSrc1 = Kb + ((size_t)bh*2048 + half*1024 + c1*8 + srow)*64 + scol;
    vSrc0 = Vt + ((size_t)bh*64 + c0*8 + srow)*2048 + half*1024 + scol;
    vSrc1 = Vt + ((size_t)bh*64 + c1*8 + srow)*2048 + half*1024 + scol;
  }
  const int ld0 = (wq*2)*512 + l*8, ld1 = (wq*2+1)*512 + l*8;

  auto stage = [&](int buf){
    async16(kSrc0, &Kls[half][buf][ld0]);
    async16(kSrc1, &Kls[half][buf][ld1]);
    async16(vSrc0, &Vls[half][buf][ld0]);
    async16(vSrc1, &Vls[half][buf][ld1]);
    kSrc0 += 4096; kSrc1 += 4096;
    vSrc0 += 64;   vSrc1 += 64;
  };

  stage(0);
  __syncthreads();
  int cur = 0;

  const int rg0 = (qc&7);   // read-swizzle key

  for (int ktl=0; ktl<16; ++ktl){
    if (ktl < 15) stage(cur^1);

    // C-init = mask (pre-scaled by LOG2E): S comes out of MFMA already masked
    f32x16 sacc[2];
    #pragma unroll
    for (int t2=0;t2<2;t2++){
      #pragma unroll
      for (int rg=0;rg<4;rg++){
        const float4 mv = *(const float4*)&maskLS[half*1024 + ktl*64 + t2*32 + rg*8 + hi*4];
        sacc[t2][rg*4+0] = mv.x;
        sacc[t2][rg*4+1] = mv.y;
        sacc[t2][rg*4+2] = mv.z;
        sacc[t2][rg*4+3] = mv.w;
      }
    }

    __builtin_amdgcn_s_setprio(1);
    #pragma unroll
    for (int ks=0; ks<4; ++ks){
      const short8 kf0 = *(const short8*)(&Kls[half][cur][ qc*64      + (((ks*2+hi)^rg0)*8) ]);
      const short8 kf1 = *(const short8*)(&Kls[half][cur][ (32+qc)*64 + (((ks*2+hi)^rg0)*8) ]);
      sacc[0] = __builtin_amdgcn_mfma_f32_32x32x16_bf16(kf0, qf[ks], sacc[0], 0,0,0);
      sacc[1] = __builtin_amdgcn_mfma_f32_32x32x16_bf16(kf1, qf[ks], sacc[1], 0,0,0);
    }
    __builtin_amdgcn_s_setprio(0);

    // max-free softmax: e = 2^(s - m_r); guard on row-sum instead of row-max
    float rs = 0.f;
    #pragma unroll
    for (int t2=0;t2<2;t2++)
      #pragma unroll
      for (int i=0;i<16;i++){
        float e = __builtin_amdgcn_exp2f(sacc[t2][i] - m_r);
        sacc[t2][i] = e;
        rs += e;
      }
    { float a = rs, c2 = rs;
      asm("v_permlane32_swap_b32 %0, %1" : "+v"(a), "+v"(c2));
      rs = a + c2; }

    if (__builtin_expect(!__all(rs <= 16777216.0f), 0)){
      float cm = 1.0f;
      #pragma unroll
      for (int t2=0;t2<2;t2++)
        #pragma unroll
        for (int i=0;i<16;i++) cm = fmaxf(cm, sacc[t2][i]);
      { float a = cm, c2 = cm;
        asm("v_permlane32_swap_b32 %0, %1" : "+v"(a), "+v"(c2));
        cm = fmaxf(a, c2); }
      float rin = 1.0f/cm;
      #pragma unroll
      for (int t2=0;t2<2;t2++)
        #pragma unroll
        for (int i=0;i<16;i++) sacc[t2][i] *= rin;
      #pragma unroll
      for (int t3=0;t3<2;t3++)
        #pragma unroll
        for (int i=0;i<16;i++) oacc[t3][i] *= rin;
      l_r *= rin;
      rs  *= rin;
      m_r += log2f(cm);
    }
    l_r += rs;

    // P -> PV B-fragments fully in-register
    short8 pB[4];
    #pragma unroll
    for (int t2=0;t2<2;t2++){
      #pragma unroll
      for (int hf=0; hf<2; ++hf){
        unsigned x0,x1,x2,x3;
        asm("v_cvt_pk_bf16_f32 %0, %1, %2" : "=v"(x0) : "v"(sacc[t2][hf*8+0]), "v"(sacc[t2][hf*8+1]));
        asm("v_cvt_pk_bf16_f32 %0, %1, %2" : "=v"(x1) : "v"(sacc[t2][hf*8+2]), "v"(sacc[t2][hf*8+3]));
        asm("v_cvt_pk_bf16_f32 %0, %1, %2" : "=v"(x2) : "v"(sacc[t2][hf*8+4]), "v"(sacc[t2][hf*8+5]));
        asm("v_cvt_pk_bf16_f32 %0, %1, %2" : "=v"(x3) : "v"(sacc[t2][hf*8+6]), "v"(sacc[t2][hf*8+7]));
        asm("v_permlane32_swap_b32 %0, %1" : "+v"(x2), "+v"(x0));
        asm("v_permlane32_swap_b32 %0, %1" : "+v"(x3), "+v"(x1));
        union { unsigned u[4]; short8 v; } pb;
        pb.u[0]=x0; pb.u[1]=x1; pb.u[2]=x2; pb.u[3]=x3;
        pB[t2*2+hf] = pb.v;
      }
    }

    // O^T += V^T P^T
    __builtin_amdgcn_s_setprio(1);
    #pragma unroll
    for (int t3=0;t3<2;t3++){
      #pragma unroll
      for (int si=0; si<4; ++si){
        const short8 vf = *(const short8*)(&Vls[half][cur][ (t3*32+qc)*64 + (((si*2+hi)^rg0)*8) ]);
        oacc[t3] = __builtin_amdgcn_mfma_f32_32x32x16_bf16(vf, pB[si], oacc[t3], 0,0,0);
      }
    }
    __builtin_amdgcn_s_setprio(0);

    __syncthreads();
    cur ^= 1;
  }

  // ---- combine halves through LDS (reuse K/V buffers) ----
  float* Ox  = (float*)&Kls[0][0][0];   // 32 KB: [wq][32 q][64 d] swizzled
  float* MLf = (float*)&Vls[0][0][0];   // [wq][ {m:32, l:32} ]

  if (half == 1){
    #pragma unroll
    for (int t3=0;t3<2;t3++){
      #pragma unroll
      for (int rg=0;rg<4;rg++){
        int dbase = t3*32 + rg*8 + hi*4;
        f32x4 o4 = { oacc[t3][rg*4+0], oacc[t3][rg*4+1], oacc[t3][rg*4+2], oacc[t3][rg*4+3] };
        *(f32x4*)&Ox[wq*2048 + qc*64 + (dbase ^ (rg0*8))] = o4;
      }
    }
    if (hi == 0){
      MLf[wq*64 + qc]      = m_r;
      MLf[wq*64 + 32 + qc] = l_r;
    }
  }
  __syncthreads();

  if (half == 0){
    float m1 = MLf[wq*64 + qc];
    float l1 = MLf[wq*64 + 32 + qc];
    float mstar = fmaxf(m_r, m1);
    float s0 = __builtin_amdgcn_exp2f(m_r - mstar);
    float s1 = __builtin_amdgcn_exp2f(m1 - mstar);
    float inv = 1.0f / (l_r*s0 + l1*s1);
    float a0 = s0*inv, a1 = s1*inv;

    int qglob = qt*128 + wq*32 + qc;
    unsigned short* cp = ctx + ((size_t)b*2048 + qglob)*1024 + h*64;
    #pragma unroll
    for (int t3=0;t3<2;t3++){
      #pragma unroll
      for (int rg=0;rg<4;rg++){
        int dbase = t3*32 + rg*8 + hi*4;
        f32x4 o1 = *(const f32x4*)&Ox[wq*2048 + qc*64 + (dbase ^ (rg0*8))];
        union { unsigned short u[4]; unsigned long long ull; } pk4;
        #pragma unroll
        for (int i=0;i<4;i++) pk4.u[i] = f2bf(oacc[t3][rg*4+i]*a0 + o1[i]*a1);
        *(unsigned long long*)(cp + dbase) = pk4.ull;
      }
    }
  }
}

// ---------------- proj GEMM: 64x128 tile, 512 threads; residual from bf16 hb; X bf16 ----
__global__ __launch_bounds__(512) void gemm_proj(
    const unsigned short* __restrict__ ctxb, const unsigned short* __restrict__ wdb,
    const float* __restrict__ bd, const unsigned short* __restrict__ hb,
    unsigned short* __restrict__ X)
{
  const int flat = blockIdx.x;              // 0..511
  const int work = (flat&7)*64 + (flat>>3);
  const int bn = work & 7;
  const int bm = work >> 3;

  __shared__ unsigned short As[3][64*32];
  __shared__ unsigned short Bs[3][128*32];
  const int tid = threadIdx.x;
  const int w = tid>>6, l = tid&63;
  const int wr = w>>2, wc = w&3;

  const f32x4 zero = {0.f,0.f,0.f,0.f};
  f32x4 acc[2][2];
  #pragma unroll
  for (int mi=0;mi<2;mi++)
    #pragma unroll
    for (int ni=0;ni<2;ni++) acc[mi][ni] = zero;

  auto stage = [&](int buf, int kt){
    if (tid < 256)
      async16(ctxb + (size_t)(bm*64 + (tid>>2))*1024 + kt*32 + (tid&3)*8, As[buf] + tid*8);
    async16(wdb + (size_t)(bn*128 + (tid>>2))*1024 + kt*32 + (tid&3)*8, Bs[buf] + tid*8);
  };

  stage(0, 0);

  int cur = 0;
  for (int kt=0; kt<32; ++kt){
    int nxt = (cur==2) ? 0 : cur+1;
    if (kt < 31){
      stage(nxt, kt+1);
      if (w < 4) ASM_VMCNT2(); else ASM_VMCNT1();
    } else {
      ASM_VMCNT0();
    }
    __builtin_amdgcn_s_barrier();
    __builtin_amdgcn_sched_barrier(0);

    short8 af[2], bf[2];
    #pragma unroll
    for (int mi=0;mi<2;mi++)
      af[mi] = *(const short8*)(As[cur] + (wr*32 + mi*16 + (l&15))*32 + (l>>4)*8);
    #pragma unroll
    for (int ni=0;ni<2;ni++)
      bf[ni] = *(const short8*)(Bs[cur] + (wc*32 + ni*16 + (l&15))*32 + (l>>4)*8);
    #pragma unroll
    for (int mi=0;mi<2;mi++)
      #pragma unroll
      for (int ni=0;ni<2;ni++)
        acc[mi][ni] = __builtin_amdgcn_mfma_f32_16x16x32_bf16(af[mi], bf[ni], acc[mi][ni], 0,0,0);

    cur = nxt;
  }

  #pragma unroll
  for (int mi=0;mi<2;mi++){
    #pragma unroll
    for (int ni=0;ni<2;ni++){
      #pragma unroll
      for (int r=0;r<4;r++){
        int mr = bm*64 + wr*32 + mi*16 + (l>>4)*4 + r;
        int nc = bn*128 + wc*32 + ni*16 + (l&15);
        float v = acc[mi][ni][r] + bd[nc] + bf2f(hb[(size_t)mr*1024 + nc]);
        X[(size_t)mr*1024 + nc] = f2bf(v);
      }
    }
  }
}

// ---------------- LayerNorm over 1024 (bf16 X in, fp32 out), one block per row ----------------
__global__ __launch_bounds__(256) void ln_kernel(
    const unsigned short* __restrict__ X, const float* __restrict__ gamma,
    const float* __restrict__ beta, float* __restrict__ out)
{
  const int row = blockIdx.x;
  const int tid = threadIdx.x;
  uint2 raw = ((const uint2*)(X + (size_t)row*1024))[tid];
  float v0 = __builtin_bit_cast(float, (raw.x & 0xFFFFu) << 16);
  float v1 = __builtin_bit_cast(float, raw.x & 0xFFFF0000u);
  float v2 = __builtin_bit_cast(float, (raw.y & 0xFFFFu) << 16);
  float v3 = __builtin_bit_cast(float, raw.y & 0xFFFF0000u);
  float s  = v0+v1+v2+v3;
  float ss = v0*v0 + v1*v1 + v2*v2 + v3*v3;
  #pragma unroll
  for (int off=1; off<64; off<<=1){
    s  += __shfl_xor(s, off);
    ss += __shfl_xor(ss, off);
  }
  __shared__ float red[8];
  const int w = tid>>6, l = tid&63;
  if (l == 0){ red[w] = s; red[4+w] = ss; }
  __syncthreads();
  s  = red[0]+red[1]+red[2]+red[3];
  ss = red[4]+red[5]+red[6]+red[7];
  float mu  = s*(1.f/1024.f);
  float var = ss*(1.f/1024.f) - mu*mu;
  float inv = rsqrtf(var + 1e-12f);
  const float4 g  = ((const float4*)gamma)[tid];
  const float4 bt = ((const float4*)beta)[tid];
  float4 oo;
  oo.x = (v0-mu)*inv*g.x + bt.x;
  oo.y = (v1-mu)*inv*g.y + bt.y;
  oo.z = (v2-mu)*inv*g.z + bt.z;
  oo.w = (v3-mu)*inv*g.w + bt.w;
  ((float4*)(out + (size_t)row*1024))[tid] = oo;
}

extern "C" void kernel_launch(void* const* d_in, const int* in_sizes, int n_in,
                              void* d_out, int out_size, void* d_ws, size_t ws_size,
                              hipStream_t stream) {
  const float* hidden  = (const float*)d_in[0];
  const float* encoder = (const float*)d_in[1];
  const float* mask    = (const float*)d_in[2];
  const float* sp      = (const float*)d_in[3];
  const float* csp     = (const float*)d_in[4];
  const float* Wq = (const float*)d_in[5];  const float* bq = (const float*)d_in[6];
  const float* Wk = (const float*)d_in[7];  const float* bk = (const float*)d_in[8];
  const float* Wv = (const float*)d_in[9];  const float* bv = (const float*)d_in[10];
  const float* Wd = (const float*)d_in[11]; const float* bd = (const float*)d_in[12];
  const float* gamma = (const float*)d_in[13];
  const float* beta  = (const float*)d_in[14];

  char* ws = (char*)d_ws;
  const size_t MB_ = 1ull<<20;
  unsigned short* hb  = (unsigned short*)(ws + 0);        // 8 MB (stays live for residual)
  unsigned short* eb  = (unsigned short*)(ws + 8*MB_);    // 8 MB; reused as ctx after qkv
  unsigned short* wqb = (unsigned short*)(ws + 16*MB_);   // 2 MB
  unsigned short* wkb = (unsigned short*)(ws + 18*MB_);   // 2 MB
  unsigned short* wvb = (unsigned short*)(ws + 20*MB_);   // 2 MB
  unsigned short* wdb = (unsigned short*)(ws + 22*MB_);   // 2 MB
  unsigned short* Qb  = (unsigned short*)(ws + 24*MB_);   // 8 MB; reused as X (bf16) after flash
  unsigned short* Kb  = (unsigned short*)(ws + 32*MB_);   // 8 MB
  unsigned short* Vt  = (unsigned short*)(ws + 40*MB_);   // 8 MB
  unsigned short* ctxb = eb;
  unsigned short* X = Qb;
  float* maskE = (float*)(ws + 48*MB_);                   // 16 KB

  prep_kernel<<<6148,256,0,stream>>>(hidden, hb, encoder, eb,
                                     Wq, wqb, Wk, wkb, Wv, wvb, Wd, wdb,
                                     mask, maskE);

  gemm_qkv<<<768,512,0,stream>>>(hb, eb, wqb, wkb, wvb,
                                 bq, bk, bv, sp, csp, Qb, Kb, Vt);
  flash_attn<<<512,512,0,stream>>>(Qb, Kb, Vt, maskE, ctxb);
  gemm_proj<<<512,512,0,stream>>>(ctxb, wdb, bd, hb, X);
  ln_kernel<<<4096,256,0,stream>>>(X, gamma, beta, (float*)d_out);
}